// Round 5
// baseline (7166.216 us; speedup 1.0000x reference)
//
#include <hip/hip_runtime.h>

#define Bz 64
#define Sz 512
#define Iz 512
#define Hz 1024
#define Lz 6
#define FB 520   // flag stride per layer

typedef __attribute__((ext_vector_type(8))) short bf16x8;
typedef __attribute__((ext_vector_type(4))) float f32x4;

__device__ __forceinline__ unsigned short f2bf(float f) {
  unsigned u = __float_as_uint(f);
  u += 0x7fffu + ((u >> 16) & 1u);
  return (unsigned short)(u >> 16);
}
// pack two f32 -> bf16 pair (round-half-up, MFMA-input quality)
__device__ __forceinline__ unsigned pkrnd(float lo, float hi) {
  return ((__float_as_uint(lo) + 0x8000u) >> 16) |
         ((__float_as_uint(hi) + 0x8000u) & 0xffff0000u);
}

// Pre-swizzled bf16 weights: element (col,k) stored at [col][k ^ ((col&7)<<3)]
// so a LINEAR global_load_lds produces the XOR-swizzled LDS tile directly.
__global__ void init_kernel(const float* __restrict__ wih, const float* __restrict__ bih,
                            const float* __restrict__ whh, const float* __restrict__ bhh,
                            const float* __restrict__ bout,
                            unsigned short* __restrict__ Wbf,
                            unsigned short* __restrict__ Wihbf,
                            unsigned int* __restrict__ hbuf32,
                            float* __restrict__ bias0, float* __restrict__ bias1,
                            float* __restrict__ out, int* __restrict__ flags, int nflags) {
  int tid = blockIdx.x * blockDim.x + threadIdx.x;
  int nt = gridDim.x * blockDim.x;
  for (int i = tid; i < Hz * Hz; i += nt) {
    int col = i >> 10, k = i & 1023;
    Wbf[(col << 10) | (k ^ ((col & 7) << 3))] = f2bf(whh[i]);
  }
  for (int i = tid; i < Hz * Iz; i += nt) {
    int col = i >> 9, k = i & 511;
    Wihbf[(col << 9) | (k ^ ((col & 7) << 3))] = f2bf(wih[i]);
  }
  // 4-slot h ring, all zero (slot l%4 region [l] is the t=0 h_prev)
  for (int i = tid; i < (4 * Lz * Bz * Hz) / 2; i += nt) hbuf32[i] = 0u;
  for (int i = tid; i < Hz; i += nt) {
    bias0[i] = bih[i] + bhh[i];   // layer 0
    bias1[i] = 2.0f * bhh[i];     // layers 1..5 (bias added twice in ref)
  }
  float b0 = bout[0];
  for (int i = tid; i < Bz * Sz; i += nt) out[i] = b0;
  for (int i = tid; i < nflags; i += nt) flags[i] = 0;
}

// GEMM for one cell: 64 rows x 64 cols, K=1024, A gathered global->reg (7-deep
// ring), W from swizzled LDS. DUAL folds (h[l-1]+h[l])@W^T into two MFMA streams.
template <bool DUAL>
__device__ __forceinline__ void cell_gemm(const unsigned short* pA, const unsigned short* pB,
                                          const unsigned short* Wl, int cc, int gg,
                                          f32x4 acc[4]) {
  const int ksw = (cc & 7) << 3;
  uint4 a1[7][2], a2[7][2];
#pragma unroll
  for (int c = 0; c < 6; ++c) {
    a1[c][0] = *(const uint4*)(pA + c * 64);
    a1[c][1] = *(const uint4*)(pA + c * 64 + 32);
    if (DUAL) {
      a2[c][0] = *(const uint4*)(pB + c * 64);
      a2[c][1] = *(const uint4*)(pB + c * 64 + 32);
    }
  }
#pragma unroll
  for (int c = 0; c < 16; ++c) {
    if (c + 6 < 16) {
      const int s2 = (c + 6) % 7;
      a1[s2][0] = *(const uint4*)(pA + (c + 6) * 64);
      a1[s2][1] = *(const uint4*)(pA + (c + 6) * 64 + 32);
      if (DUAL) {
        a2[s2][0] = *(const uint4*)(pB + (c + 6) * 64);
        a2[s2][1] = *(const uint4*)(pB + (c + 6) * 64 + 32);
      }
    }
    const int s = c % 7;
#pragma unroll
    for (int ks = 0; ks < 2; ++ks) {
      const int kof = c * 64 + ((ks * 32 + gg * 8) ^ ksw);
      bf16x8 bfr[4];
#pragma unroll
      for (int n = 0; n < 4; ++n)
        bfr[n] = *(const bf16x8*)(Wl + (n * 16 + cc) * 1024 + kof);
      const bf16x8 af1 = __builtin_bit_cast(bf16x8, a1[s][ks]);
#pragma unroll
      for (int n = 0; n < 4; ++n)
        acc[n] = __builtin_amdgcn_mfma_f32_16x16x32_bf16(af1, bfr[n], acc[n], 0, 0, 0);
      if (DUAL) {
        const bf16x8 af2 = __builtin_bit_cast(bf16x8, a2[s][ks]);
#pragma unroll
        for (int n = 0; n < 4; ++n)
          acc[n] = __builtin_amdgcn_mfma_f32_16x16x32_bf16(af2, bfr[n], acc[n], 0, 0, 0);
      }
    }
  }
}

// Persistent self-timed wavefront kernel.
// xcd = bid%8. XCD l<6: 16 WGs = layer l (64-col W_hh slice each, LDS-resident).
// XCD 6: 16 xproj WGs (64-col W_ih slice; xq[t&3] = x_t @ W_ih^T, 4 ahead).
// XCD 7: idle. Flags F[l][b] / X[t] count to 16, AGENT scope.
// h ring: 4 slots; beat b reads slot b&3, writes slot (b+1)&3. WAR protection:
// slot (b+1)&3 was written at beat b-4, its readers ran at beat b-3 ->
// gate on F[l+1][b-3] (self covered by program order).
__global__ __launch_bounds__(256, 1) void rnn_kernel(
    const float* __restrict__ x,
    const unsigned short* __restrict__ Wbf,
    const unsigned short* __restrict__ Wihbf,
    unsigned short* __restrict__ hbuf, float* __restrict__ xq,
    const float* __restrict__ bias0, const float* __restrict__ bias1,
    const float* __restrict__ wout,
    float* __restrict__ dout, int* __restrict__ F, int* __restrict__ X) {
  extern __shared__ char lds[];
  unsigned short* Wl = (unsigned short*)lds;

  const int bid = blockIdx.x;
  const int xcd = bid & 7;
  const int slot = bid >> 3;  // 0..15
  const int tid = threadIdx.x;
  const int lane = tid & 63;
  const int wav = tid >> 6;
  const int cc = lane & 15;
  const int gg = lane >> 4;
  const int ra = wav * 16 + cc;  // batch row this lane gathers / epilogue col base

  if (xcd == 7) return;

  if (xcd < 6) {
    // ================= layer worker =================
    const int layer = xcd;
    const int c0 = slot << 6;  // 64 output cols
    // stage W_hh slice once: [64][1024] bf16 pre-swizzled, linear copy
    {
      const unsigned short* wsrc = Wbf + ((size_t)c0 << 10);
      for (int i = 0; i < 32; ++i) {
        const int off = (i * 256 + tid) * 8;
        __builtin_amdgcn_global_load_lds(wsrc + off, Wl + off, 16, 0, 0);
      }
      asm volatile("s_waitcnt vmcnt(0)" ::: "memory");
    }
    __syncthreads();
    // constants in registers (survive per-beat cache invalidates)
    float bv[4], wv[4];
#pragma unroll
    for (int n = 0; n < 4; ++n) {
      const int col = c0 + n * 16 + cc;
      bv[n] = (layer == 0) ? bias0[col] : bias1[col];
      wv[n] = (layer == Lz - 1) ? wout[col] : 0.f;
    }

    for (int t = 0; t < Sz; ++t) {
      const int b = t + layer;
      // ---- acquire gate
      if (tid == 0) {
        if (layer == 0) {
          while (__hip_atomic_load(&X[t], __ATOMIC_RELAXED, __HIP_MEMORY_SCOPE_AGENT) < 16)
            __builtin_amdgcn_s_sleep(2);
        } else {
          while (__hip_atomic_load(&F[(layer - 1) * FB + b - 1], __ATOMIC_RELAXED,
                                   __HIP_MEMORY_SCOPE_AGENT) < 16)
            __builtin_amdgcn_s_sleep(2);
        }
        if (t >= 1) {  // sibling WGs of own layer done with beat b-1
          while (__hip_atomic_load(&F[layer * FB + b - 1], __ATOMIC_RELAXED,
                                   __HIP_MEMORY_SCOPE_AGENT) < 16)
            __builtin_amdgcn_s_sleep(2);
        }
        if (layer < Lz - 1 && t >= 4) {  // WAR: consumer finished with slot (b+1)&3
          while (__hip_atomic_load(&F[(layer + 1) * FB + b - 3], __ATOMIC_RELAXED,
                                   __HIP_MEMORY_SCOPE_AGENT) < 16)
            __builtin_amdgcn_s_sleep(2);
        }
        __builtin_amdgcn_fence(__ATOMIC_ACQUIRE, "agent");  // inv L1+L2 (fresh h/xq)
      }
      __syncthreads();

      const unsigned short* hrd = hbuf + (size_t)(b & 3) * (Lz * Bz * Hz);
      unsigned short* hwr = hbuf + (size_t)((b + 1) & 3) * (Lz * Bz * Hz);
      const unsigned short* pA =
          hrd + ((size_t)((layer > 0 ? layer - 1 : 0) * Bz + ra)) * Hz + gg * 8;
      const unsigned short* pB = hrd + ((size_t)(layer * Bz + ra)) * Hz + gg * 8;

      f32x4 acc[4];
#pragma unroll
      for (int n = 0; n < 4; ++n) acc[n] = (f32x4){0.f, 0.f, 0.f, 0.f};
      if (layer == 0)
        cell_gemm<false>(pA, pB, Wl, cc, gg, acc);
      else
        cell_gemm<true>(pA, pB, Wl, cc, gg, acc);

      // ---- epilogue
      float hv[4][4];
#pragma unroll
      for (int n = 0; n < 4; ++n) {
        const int col = c0 + n * 16 + cc;
#pragma unroll
        for (int i = 0; i < 4; ++i) {
          const int brow = wav * 16 + gg * 4 + i;
          float z = acc[n][i] + bv[n];
          if (layer == 0)
            z += xq[(size_t)(t & 3) * (Bz * Hz) + (size_t)brow * Hz + col];
          const float v = tanhf(z);
          hv[n][i] = v;
          hwr[((size_t)layer * Bz + brow) * Hz + col] = f2bf(v);
          if (t == Sz - 1)
            dout[Bz * Sz + ((size_t)layer * Bz + brow) * Hz + col] = v;
        }
      }
      if (layer == Lz - 1) {
#pragma unroll
        for (int i = 0; i < 4; ++i) {
          float pv = hv[0][i] * wv[0] + hv[1][i] * wv[1] + hv[2][i] * wv[2] + hv[3][i] * wv[3];
          pv += __shfl_xor(pv, 1);
          pv += __shfl_xor(pv, 2);
          pv += __shfl_xor(pv, 4);
          pv += __shfl_xor(pv, 8);
          if (cc == 0) {
            const int brow = wav * 16 + gg * 4 + i;
            atomicAdd(&dout[(size_t)brow * Sz + t], pv);
          }
        }
      }
      // ---- release: drain stores, fence (wbl2), then flag
      asm volatile("s_waitcnt vmcnt(0)" ::: "memory");
      __syncthreads();
      if (tid == 0) {
        __builtin_amdgcn_fence(__ATOMIC_RELEASE, "agent");
        __hip_atomic_fetch_add(&F[layer * FB + b], 1, __ATOMIC_RELAXED,
                               __HIP_MEMORY_SCOPE_AGENT);
      }
    }
  } else {
    // ================= xproj worker (xcd == 6) =================
    const int xc0 = slot << 6;  // 64 cols of H
    {
      const unsigned short* wsrc = Wihbf + ((size_t)xc0 << 9);
      for (int i = 0; i < 16; ++i) {
        const int off = (i * 256 + tid) * 8;
        __builtin_amdgcn_global_load_lds(wsrc + off, Wl + off, 16, 0, 0);
      }
      asm volatile("s_waitcnt vmcnt(0)" ::: "memory");
    }
    __syncthreads();
    const int ksw = (cc & 7) << 3;

    for (int tx = 0; tx < Sz; ++tx) {
      if (tx >= 4) {  // xq ring WAR guard: slot tx&3 free once layer-0 beat tx-4 done
        if (tid == 0) {
          while (__hip_atomic_load(&F[0 * FB + tx - 4], __ATOMIC_RELAXED,
                                   __HIP_MEMORY_SCOPE_AGENT) < 16)
            __builtin_amdgcn_s_sleep(2);
        }
        __syncthreads();
      }
      const float* xrow = x + ((size_t)ra * Sz + tx) * Iz + gg * 8;
      f32x4 acc[4];
#pragma unroll
      for (int n = 0; n < 4; ++n) acc[n] = (f32x4){0.f, 0.f, 0.f, 0.f};
      float4 xr[3][4];
#pragma unroll
      for (int c = 0; c < 2; ++c) {
#pragma unroll
        for (int q = 0; q < 2; ++q) {
          xr[c][2 * q + 0] = *(const float4*)(xrow + c * 64 + q * 32);
          xr[c][2 * q + 1] = *(const float4*)(xrow + c * 64 + q * 32 + 4);
        }
      }
#pragma unroll
      for (int c = 0; c < 8; ++c) {
        if (c + 2 < 8) {
          const int s2 = (c + 2) % 3;
#pragma unroll
          for (int q = 0; q < 2; ++q) {
            xr[s2][2 * q + 0] = *(const float4*)(xrow + (c + 2) * 64 + q * 32);
            xr[s2][2 * q + 1] = *(const float4*)(xrow + (c + 2) * 64 + q * 32 + 4);
          }
        }
        const int s = c % 3;
#pragma unroll
        for (int ks = 0; ks < 2; ++ks) {
          const float4 f0 = xr[s][2 * ks + 0];
          const float4 f1 = xr[s][2 * ks + 1];
          uint4 pk;
          pk.x = pkrnd(f0.x, f0.y);
          pk.y = pkrnd(f0.z, f0.w);
          pk.z = pkrnd(f1.x, f1.y);
          pk.w = pkrnd(f1.z, f1.w);
          const bf16x8 af = __builtin_bit_cast(bf16x8, pk);
          const int kof = c * 64 + ((ks * 32 + gg * 8) ^ ksw);
#pragma unroll
          for (int n = 0; n < 4; ++n) {
            const bf16x8 bf = *(const bf16x8*)(Wl + (n * 16 + cc) * 512 + kof);
            acc[n] = __builtin_amdgcn_mfma_f32_16x16x32_bf16(af, bf, acc[n], 0, 0, 0);
          }
        }
      }
      float* xdst = xq + (size_t)(tx & 3) * (Bz * Hz);
#pragma unroll
      for (int n = 0; n < 4; ++n)
#pragma unroll
        for (int i = 0; i < 4; ++i) {
          const int brow = wav * 16 + gg * 4 + i;
          xdst[(size_t)brow * Hz + xc0 + n * 16 + cc] = acc[n][i];
        }
      asm volatile("s_waitcnt vmcnt(0)" ::: "memory");
      __syncthreads();
      if (tid == 0) {
        __builtin_amdgcn_fence(__ATOMIC_RELEASE, "agent");
        __hip_atomic_fetch_add(&X[tx], 1, __ATOMIC_RELAXED, __HIP_MEMORY_SCOPE_AGENT);
      }
    }
  }
}

extern "C" void kernel_launch(void* const* d_in, const int* in_sizes, int n_in,
                              void* d_out, int out_size, void* d_ws, size_t ws_size,
                              hipStream_t stream) {
  (void)in_sizes; (void)n_in; (void)out_size; (void)ws_size;
  const float* x    = (const float*)d_in[0];
  const float* wih  = (const float*)d_in[1];
  const float* bih  = (const float*)d_in[2];
  const float* whh  = (const float*)d_in[3];
  const float* bhh  = (const float*)d_in[4];
  const float* wout = (const float*)d_in[5];
  const float* bout = (const float*)d_in[6];
  float* out = (float*)d_out;
  char* ws = (char*)d_ws;
  // ws: [0,2M) Wbf | [2M,3M) Wihbf | [3M,6M) h ring bf16[4][L][B][H] |
  //     [6M,7M) xq ring f32[4][B][H] | [7M,+8K) bias0/1 | [7M+16K) flags
  unsigned short* Wbf   = (unsigned short*)(ws);
  unsigned short* Wihbf = (unsigned short*)(ws + ((size_t)2 << 20));
  unsigned short* hbuf  = (unsigned short*)(ws + ((size_t)3 << 20));
  float* xq    = (float*)(ws + ((size_t)6 << 20));
  float* bias0 = (float*)(ws + ((size_t)7 << 20));
  float* bias1 = bias0 + Hz;
  int* F = (int*)(ws + ((size_t)7 << 20) + 16384);  // [6][FB]
  int* X = F + Lz * FB;                             // [512]
  const int nflags = Lz * FB + Sz;

  (void)hipFuncSetAttribute((const void*)rnn_kernel,
                            hipFuncAttributeMaxDynamicSharedMemorySize, 131072);
  (void)hipGetLastError();

  hipLaunchKernelGGL(init_kernel, dim3(1024), dim3(256), 0, stream,
                     wih, bih, whh, bhh, bout, Wbf, Wihbf,
                     (unsigned int*)hbuf, bias0, bias1, out, F, nflags);
  hipLaunchKernelGGL(rnn_kernel, dim3(128), dim3(256), 131072, stream,
                     x, Wbf, Wihbf, hbuf, xq, bias0, bias1, wout, out, F, X);
}

// Round 8
// 6719.437 us; speedup vs baseline: 1.0665x; 1.0665x over previous
//
#include <hip/hip_runtime.h>

#define Bz 64
#define Sz 512
#define Iz 512
#define Hz 1024
#define Lz 6
#define FB 520   // flag stride per layer

typedef __attribute__((ext_vector_type(8))) short bf16x8;
typedef __attribute__((ext_vector_type(4))) float f32x4;

__device__ __forceinline__ unsigned short f2bf(float f) {
  unsigned u = __float_as_uint(f);
  u += 0x7fffu + ((u >> 16) & 1u);
  return (unsigned short)(u >> 16);
}
__device__ __forceinline__ unsigned pkrnd(float lo, float hi) {
  return ((__float_as_uint(lo) + 0x8000u) >> 16) |
         ((__float_as_uint(hi) + 0x8000u) & 0xffff0000u);
}

// ---- asm helpers: LLC-direct (sc0 sc1 = bypass L1+L2) dataflow ----
template <int N>
__device__ __forceinline__ void vmwait() {
  asm volatile("s_waitcnt vmcnt(%0)" ::"n"(N) : "memory");
  __builtin_amdgcn_sched_barrier(0);
}
template <int OFF>
__device__ __forceinline__ uint4 ld16llc(const void* p) {
  uint4 r;
  asm volatile("global_load_dwordx4 %0, %1, off offset:%2 sc0 sc1"
               : "=&v"(r) : "v"(p), "n"(OFF));
  return r;
}
__device__ __forceinline__ float ldf_llc(const float* p) {
  float r;
  asm volatile("global_load_dword %0, %1, off sc0 sc1" : "=&v"(r) : "v"(p));
  return r;
}
__device__ __forceinline__ void stf_llc(float* p, float v) {
  asm volatile("global_store_dword %0, %1, off sc0 sc1" ::"v"(p), "v"(v) : "memory");
}
__device__ __forceinline__ void st2llc(void* p, unsigned v) {
  asm volatile("global_store_short %0, %1, off sc0 sc1" ::"v"(p), "v"(v) : "memory");
}

#define MFMA(a, b, c) __builtin_amdgcn_mfma_f32_16x16x32_bf16(a, b, c, 0, 0, 0)
#define BC(u) __builtin_bit_cast(bf16x8, u)

// Pre-swizzled bf16 weights: (col,k) stored at [col][k ^ ((col&7)<<3)] so a
// LINEAR global_load_lds produces the XOR-swizzled LDS tile directly.
__global__ void init_kernel(const float* __restrict__ wih, const float* __restrict__ bih,
                            const float* __restrict__ whh, const float* __restrict__ bhh,
                            const float* __restrict__ bout,
                            unsigned short* __restrict__ Wbf,
                            unsigned short* __restrict__ Wihbf,
                            unsigned int* __restrict__ hbuf32,
                            float* __restrict__ bias0, float* __restrict__ bias1,
                            float* __restrict__ out, int* __restrict__ flags, int nflags) {
  int tid = blockIdx.x * blockDim.x + threadIdx.x;
  int nt = gridDim.x * blockDim.x;
  for (int i = tid; i < Hz * Hz; i += nt) {
    int col = i >> 10, k = i & 1023;
    Wbf[(col << 10) | (k ^ ((col & 7) << 3))] = f2bf(whh[i]);
  }
  for (int i = tid; i < Hz * Iz; i += nt) {
    int col = i >> 9, k = i & 511;
    Wihbf[(col << 9) | (k ^ ((col & 7) << 3))] = f2bf(wih[i]);
  }
  for (int i = tid; i < (4 * Lz * Bz * Hz) / 2; i += nt) hbuf32[i] = 0u;  // 4-slot ring
  for (int i = tid; i < Hz; i += nt) {
    bias0[i] = bih[i] + bhh[i];   // layer 0
    bias1[i] = 2.0f * bhh[i];     // layers 1..5 (bias added twice in ref)
  }
  float b0 = bout[0];
  for (int i = tid; i < Bz * Sz; i += nt) out[i] = b0;
  for (int i = tid; i < nflags; i += nt) flags[i] = 0;
}

// Dual-stream cell GEMM: 16 rows(this wave) x 64 cols x K=1024,
// A1 = h[l-1]_t, A2 = h[l]_{t-1}, both LLC-direct, 6-chunk-ahead counted ring.
__device__ __forceinline__ void cell_gemm_d(const unsigned short* pA, const unsigned short* pB,
                                            const unsigned short* Wl, int cc, int gg,
                                            f32x4 acc[4]) {
  const int ksw = (cc & 7) << 3;
  const int gg8 = gg << 3;
  const unsigned short* Wl0 = Wl + (0 * 16 + cc) * 1024;
  const unsigned short* Wl1 = Wl + (1 * 16 + cc) * 1024;
  const unsigned short* Wl2 = Wl + (2 * 16 + cc) * 1024;
  const unsigned short* Wl3 = Wl + (3 * 16 + cc) * 1024;
  uint4 A1a[16], A1b[16], A2a[16], A2b[16];
#define ISSD(c) { \
    A1a[c] = ld16llc<(c) * 128>(pA);      A1b[c] = ld16llc<(c) * 128 + 64>(pA); \
    A2a[c] = ld16llc<(c) * 128>(pB);      A2b[c] = ld16llc<(c) * 128 + 64>(pB); }
#define CONS_KS(kofv, AFa, AFb) { \
    const int kof = (kofv); \
    const bf16x8 bA = *(const bf16x8*)(Wl0 + kof); \
    const bf16x8 bB = *(const bf16x8*)(Wl1 + kof); \
    const bf16x8 bC = *(const bf16x8*)(Wl2 + kof); \
    const bf16x8 bD = *(const bf16x8*)(Wl3 + kof); \
    acc[0] = MFMA(AFa, bA, acc[0]); acc[1] = MFMA(AFa, bB, acc[1]); \
    acc[2] = MFMA(AFa, bC, acc[2]); acc[3] = MFMA(AFa, bD, acc[3]); \
    acc[0] = MFMA(AFb, bA, acc[0]); acc[1] = MFMA(AFb, bB, acc[1]); \
    acc[2] = MFMA(AFb, bC, acc[2]); acc[3] = MFMA(AFb, bD, acc[3]); }
#define CONSD(c) { \
    vmwait<4 * ((((c) + 6) < 16) ? 6 : 15 - (c))>(); \
    CONS_KS((c) * 64 + (gg8 ^ ksw), BC(A1a[c]), BC(A2a[c])); \
    CONS_KS((c) * 64 + ((32 + gg8) ^ ksw), BC(A1b[c]), BC(A2b[c])); }
  ISSD(0) ISSD(1) ISSD(2) ISSD(3) ISSD(4) ISSD(5)
  ISSD(6)  CONSD(0)  ISSD(7)  CONSD(1)  ISSD(8)  CONSD(2)
  ISSD(9)  CONSD(3)  ISSD(10) CONSD(4)  ISSD(11) CONSD(5)
  ISSD(12) CONSD(6)  ISSD(13) CONSD(7)  ISSD(14) CONSD(8)
  ISSD(15) CONSD(9)
  CONSD(10) CONSD(11) CONSD(12) CONSD(13) CONSD(14) CONSD(15)
#undef ISSD
#undef CONSD
#undef CONS_KS
}

// Single-stream variant (layer 0): A1 = h[0]_{t-1}, 8-chunk-ahead ring.
__device__ __forceinline__ void cell_gemm_s(const unsigned short* pA,
                                            const unsigned short* Wl, int cc, int gg,
                                            f32x4 acc[4]) {
  const int ksw = (cc & 7) << 3;
  const int gg8 = gg << 3;
  const unsigned short* Wl0 = Wl + (0 * 16 + cc) * 1024;
  const unsigned short* Wl1 = Wl + (1 * 16 + cc) * 1024;
  const unsigned short* Wl2 = Wl + (2 * 16 + cc) * 1024;
  const unsigned short* Wl3 = Wl + (3 * 16 + cc) * 1024;
  uint4 A1a[16], A1b[16];
#define ISSS(c) { \
    A1a[c] = ld16llc<(c) * 128>(pA);      A1b[c] = ld16llc<(c) * 128 + 64>(pA); }
#define CONS_K1(kofv, AF) { \
    const int kof = (kofv); \
    const bf16x8 bA = *(const bf16x8*)(Wl0 + kof); \
    const bf16x8 bB = *(const bf16x8*)(Wl1 + kof); \
    const bf16x8 bC = *(const bf16x8*)(Wl2 + kof); \
    const bf16x8 bD = *(const bf16x8*)(Wl3 + kof); \
    acc[0] = MFMA(AF, bA, acc[0]); acc[1] = MFMA(AF, bB, acc[1]); \
    acc[2] = MFMA(AF, bC, acc[2]); acc[3] = MFMA(AF, bD, acc[3]); }
#define CONSS(c) { \
    vmwait<2 * ((((c) + 8) < 16) ? 8 : 15 - (c))>(); \
    CONS_K1((c) * 64 + (gg8 ^ ksw), BC(A1a[c])); \
    CONS_K1((c) * 64 + ((32 + gg8) ^ ksw), BC(A1b[c])); }
  ISSS(0) ISSS(1) ISSS(2) ISSS(3) ISSS(4) ISSS(5) ISSS(6) ISSS(7)
  ISSS(8)  CONSS(0)  ISSS(9)  CONSS(1)  ISSS(10) CONSS(2)  ISSS(11) CONSS(3)
  ISSS(12) CONSS(4)  ISSS(13) CONSS(5)  ISSS(14) CONSS(6)  ISSS(15) CONSS(7)
  CONSS(8) CONSS(9) CONSS(10) CONSS(11) CONSS(12) CONSS(13) CONSS(14) CONSS(15)
#undef ISSS
#undef CONSS
#undef CONS_K1
}

// Persistent self-timed wavefront kernel, placement-independent.
// Blocks 0..95: layer = bid>>4, 64-col tile = (bid&15); W_hh slice LDS-resident.
// Blocks 96..111: xproj (xq[t&3] = x_t @ W_ih^T, 4 beats ahead).
// All cross-WG h/xq traffic is LLC-direct (sc0 sc1); flags are AGENT-scope
// atomics at LLC. NO cache fences anywhere (nothing is ever dirty in L2).
// h ring: 4 slots; beat b reads slot b&3, writes slot (b+1)&3; WAR gates as R4.
__global__ __launch_bounds__(256, 1) void rnn_kernel(
    const float* __restrict__ x,
    const unsigned short* __restrict__ Wbf,
    const unsigned short* __restrict__ Wihbf,
    unsigned short* __restrict__ hbuf, float* __restrict__ xq,
    const float* __restrict__ bias0, const float* __restrict__ bias1,
    const float* __restrict__ wout,
    float* __restrict__ dout, int* __restrict__ F, int* __restrict__ X) {
  extern __shared__ char lds[];
  unsigned short* Wl = (unsigned short*)lds;

  const int bid = blockIdx.x;
  const int tid = threadIdx.x;
  const int lane = tid & 63;
  const int wav = tid >> 6;
  const int cc = lane & 15;
  const int gg = lane >> 4;
  const int ra = wav * 16 + cc;  // A row this lane gathers

  if (bid < 96) {
    // ================= layer worker =================
    const int layer = bid >> 4;
    const int c0 = (bid & 15) << 6;  // 64 output cols
    {
      const unsigned short* wsrc = Wbf + ((size_t)c0 << 10);
      for (int i = 0; i < 32; ++i) {
        const int off = (i * 256 + tid) * 8;
        __builtin_amdgcn_global_load_lds(wsrc + off, Wl + off, 16, 0, 0);
      }
      asm volatile("s_waitcnt vmcnt(0)" ::: "memory");
    }
    __syncthreads();
    float bv[4], wv[4];
#pragma unroll
    for (int n = 0; n < 4; ++n) {
      const int col = c0 + n * 16 + cc;
      bv[n] = (layer == 0) ? bias0[col] : bias1[col];
      wv[n] = (layer == Lz - 1) ? wout[col] : 0.f;
    }

    for (int t = 0; t < Sz; ++t) {
      const int b = t + layer;
      // ---- gate: lane-parallel poll (one LLC RT per iteration), no fences
      if (wav == 0) {
        const int* fp = nullptr;
        if (lane == 0) fp = (layer == 0) ? &X[t] : &F[(layer - 1) * FB + (b - 1)];
        if (lane == 1 && t >= 1) fp = &F[layer * FB + (b - 1)];
        if (lane == 2 && layer < Lz - 1 && t >= 4) fp = &F[(layer + 1) * FB + (b - 3)];
        if (fp) {
          while (__hip_atomic_load(fp, __ATOMIC_RELAXED, __HIP_MEMORY_SCOPE_AGENT) < 16)
            __builtin_amdgcn_s_sleep(1);
        }
      }
      __syncthreads();

      const unsigned short* hrd = hbuf + (size_t)(b & 3) * (Lz * Bz * Hz);
      unsigned short* hwr = hbuf + (size_t)((b + 1) & 3) * (Lz * Bz * Hz);

      f32x4 acc[4];
#pragma unroll
      for (int n = 0; n < 4; ++n) acc[n] = (f32x4){0.f, 0.f, 0.f, 0.f};
      if (layer == 0) {
        const unsigned short* pA = hrd + (size_t)ra * Hz + (gg << 3);
        cell_gemm_s(pA, Wl, cc, gg, acc);
      } else {
        const unsigned short* pA =
            hrd + ((size_t)((layer - 1) * Bz + ra)) * Hz + (gg << 3);
        const unsigned short* pB =
            hrd + ((size_t)(layer * Bz + ra)) * Hz + (gg << 3);
        cell_gemm_d(pA, pB, Wl, cc, gg, acc);
      }

      // ---- epilogue (layer 0: add xproj, LLC-direct loads)
      float xv[16];
      if (layer == 0) {
        const float* xb = xq + (size_t)(t & 3) * (Bz * Hz);
#pragma unroll
        for (int n = 0; n < 4; ++n)
#pragma unroll
          for (int i = 0; i < 4; ++i) {
            const int brow = wav * 16 + gg * 4 + i;
            xv[n * 4 + i] = ldf_llc(xb + (size_t)brow * Hz + c0 + n * 16 + cc);
          }
        vmwait<0>();
      }
      float hv[4][4];
#pragma unroll
      for (int n = 0; n < 4; ++n) {
        const int col = c0 + n * 16 + cc;
#pragma unroll
        for (int i = 0; i < 4; ++i) {
          const int brow = wav * 16 + gg * 4 + i;
          float z = acc[n][i] + bv[n];
          if (layer == 0) z += xv[n * 4 + i];
          const float v = tanhf(z);
          hv[n][i] = v;
          st2llc(hwr + ((size_t)layer * Bz + brow) * Hz + col, (unsigned)f2bf(v));
          if (t == Sz - 1)
            dout[Bz * Sz + ((size_t)layer * Bz + brow) * Hz + col] = v;
        }
      }
      if (layer == Lz - 1) {
#pragma unroll
        for (int i = 0; i < 4; ++i) {
          float pv = hv[0][i] * wv[0] + hv[1][i] * wv[1] + hv[2][i] * wv[2] + hv[3][i] * wv[3];
          pv += __shfl_xor(pv, 1);
          pv += __shfl_xor(pv, 2);
          pv += __shfl_xor(pv, 4);
          pv += __shfl_xor(pv, 8);
          if (cc == 0) {
            const int brow = wav * 16 + gg * 4 + i;
            atomicAdd(&dout[(size_t)brow * Sz + t], pv);
          }
        }
      }
      // ---- release: drain write-through stores, then LLC flag RMW
      asm volatile("s_waitcnt vmcnt(0)" ::: "memory");
      __syncthreads();
      if (tid == 0)
        __hip_atomic_fetch_add(&F[layer * FB + b], 1, __ATOMIC_RELAXED,
                               __HIP_MEMORY_SCOPE_AGENT);
    }
  } else {
    // ================= xproj worker =================
    const int xc0 = (bid - 96) << 6;  // 64 cols of H
    {
      const unsigned short* wsrc = Wihbf + ((size_t)xc0 << 9);
      for (int i = 0; i < 16; ++i) {
        const int off = (i * 256 + tid) * 8;
        __builtin_amdgcn_global_load_lds(wsrc + off, Wl + off, 16, 0, 0);
      }
      asm volatile("s_waitcnt vmcnt(0)" ::: "memory");
    }
    __syncthreads();
    const int ksw = (cc & 15 & 7) << 3;
    const int gg8 = gg << 3;

    for (int tx = 0; tx < Sz; ++tx) {
      if (tx >= 4) {  // xq ring WAR guard
        if (tid == 0) {
          while (__hip_atomic_load(&F[0 * FB + (tx - 4)], __ATOMIC_RELAXED,
                                   __HIP_MEMORY_SCOPE_AGENT) < 16)
            __builtin_amdgcn_s_sleep(1);
        }
        __syncthreads();
      }
      const float* xrow = x + ((size_t)ra * Sz + tx) * Iz + gg8;
      f32x4 acc[4];
#pragma unroll
      for (int n = 0; n < 4; ++n) acc[n] = (f32x4){0.f, 0.f, 0.f, 0.f};
      float4 xr[3][4];
#pragma unroll
      for (int c = 0; c < 2; ++c)
#pragma unroll
        for (int q = 0; q < 2; ++q) {
          xr[c][2 * q + 0] = *(const float4*)(xrow + c * 64 + q * 32);
          xr[c][2 * q + 1] = *(const float4*)(xrow + c * 64 + q * 32 + 4);
        }
#pragma unroll
      for (int c = 0; c < 8; ++c) {
        if (c + 2 < 8) {
          const int s2 = (c + 2) % 3;
#pragma unroll
          for (int q = 0; q < 2; ++q) {
            xr[s2][2 * q + 0] = *(const float4*)(xrow + (c + 2) * 64 + q * 32);
            xr[s2][2 * q + 1] = *(const float4*)(xrow + (c + 2) * 64 + q * 32 + 4);
          }
        }
        const int s = c % 3;
#pragma unroll
        for (int ks = 0; ks < 2; ++ks) {
          const float4 f0 = xr[s][2 * ks + 0];
          const float4 f1 = xr[s][2 * ks + 1];
          uint4 pk;
          pk.x = pkrnd(f0.x, f0.y);
          pk.y = pkrnd(f0.z, f0.w);
          pk.z = pkrnd(f1.x, f1.y);
          pk.w = pkrnd(f1.z, f1.w);
          const bf16x8 af = BC(pk);
          const int kof = c * 64 + ((ks * 32 + gg8) ^ ksw);
#pragma unroll
          for (int n = 0; n < 4; ++n) {
            const bf16x8 bf = *(const bf16x8*)(Wl + (n * 16 + cc) * 512 + kof);
            acc[n] = MFMA(af, bf, acc[n]);
          }
        }
      }
      float* xdst = xq + (size_t)(tx & 3) * (Bz * Hz);
#pragma unroll
      for (int n = 0; n < 4; ++n)
#pragma unroll
        for (int i = 0; i < 4; ++i) {
          const int brow = wav * 16 + gg * 4 + i;
          stf_llc(xdst + (size_t)brow * Hz + xc0 + n * 16 + cc, acc[n][i]);
        }
      asm volatile("s_waitcnt vmcnt(0)" ::: "memory");
      __syncthreads();
      if (tid == 0)
        __hip_atomic_fetch_add(&X[tx], 1, __ATOMIC_RELAXED, __HIP_MEMORY_SCOPE_AGENT);
    }
  }
}

extern "C" void kernel_launch(void* const* d_in, const int* in_sizes, int n_in,
                              void* d_out, int out_size, void* d_ws, size_t ws_size,
                              hipStream_t stream) {
  (void)in_sizes; (void)n_in; (void)out_size; (void)ws_size;
  const float* x    = (const float*)d_in[0];
  const float* wih  = (const float*)d_in[1];
  const float* bih  = (const float*)d_in[2];
  const float* whh  = (const float*)d_in[3];
  const float* bhh  = (const float*)d_in[4];
  const float* wout = (const float*)d_in[5];
  const float* bout = (const float*)d_in[6];
  float* out = (float*)d_out;
  char* ws = (char*)d_ws;
  // ws: [0,2M) Wbf | [2M,3M) Wihbf | [3M,6M) h ring bf16[4][L][B][H] |
  //     [6M,7M) xq ring f32[4][B][H] | [7M,+8K) bias0/1 | [7M+16K) flags
  unsigned short* Wbf   = (unsigned short*)(ws);
  unsigned short* Wihbf = (unsigned short*)(ws + ((size_t)2 << 20));
  unsigned short* hbuf  = (unsigned short*)(ws + ((size_t)3 << 20));
  float* xq    = (float*)(ws + ((size_t)6 << 20));
  float* bias0 = (float*)(ws + ((size_t)7 << 20));
  float* bias1 = bias0 + Hz;
  int* F = (int*)(ws + ((size_t)7 << 20) + 16384);  // [6][FB]
  int* X = F + Lz * FB;                             // [512]
  const int nflags = Lz * FB + Sz;

  (void)hipFuncSetAttribute((const void*)rnn_kernel,
                            hipFuncAttributeMaxDynamicSharedMemorySize, 131072);
  (void)hipGetLastError();

  hipLaunchKernelGGL(init_kernel, dim3(1024), dim3(256), 0, stream,
                     wih, bih, whh, bhh, bout, Wbf, Wihbf,
                     (unsigned int*)hbuf, bias0, bias1, out, F, nflags);
  hipLaunchKernelGGL(rnn_kernel, dim3(112), dim3(256), 131072, stream,
                     x, Wbf, Wihbf, hbuf, xq, bias0, bias1, wout, out, F, X);
}